// Round 1
// 397.911 us; speedup vs baseline: 1.0285x; 1.0285x over previous
//
#include <hip/hip_runtime.h>

// Problem constants (fixed by the reference):
//   x        [B=4096, D=16384] fp32
//   hashProj [D=16384, E=1024] fp32, exactly one nonzero (+-1) per row
//   out      [B=4096, E=1024]  fp32 = x @ hashProj
#define DIM_D 16384
#define DIM_E 1024
#define DIM_B 4096
#define ELL_CAP 64   // max bucket capacity; counts ~Poisson(16), P(>64) ~ 1e-50

// ---------------------------------------------------------------------------
// Workspace layout:
//   ell    [ELL_CAP * 1024] int (256 KiB)  -- transposed ELL, prefilled 0xFF (-1 pads)
//   cursor [1024] int                      -- prefilled 0xFF (-1): slot = atomicAdd+1
// Entry encoding: bits 0..13 = feature index j, bit 14 = sign (1 -> negative).
// Pad = -1 (all ones) -> decodes to +0.0f in the gather (branchless).
// ---------------------------------------------------------------------------

// K1: fused extract + fill. One wave per hashProj row: scan 1024 floats
// (coalesced float4), the single founder lane claims a slot in bucket e via
// atomicAdd and writes the packed entry. No idx/sgn arrays, no global
// atomicMax (trip counts are derived per-wave in the gather instead).
__global__ __launch_bounds__(256) void hash_extract_fill(
    const float* __restrict__ hashProj,
    int* __restrict__ cursor,
    int* __restrict__ ell) {
  const int wave = threadIdx.x >> 6;
  const int lane = threadIdx.x & 63;
  const int row = blockIdx.x * 4 + wave;   // 4096 blocks x 4 waves = 16384 rows
  const float4* rp = (const float4*)(hashProj + (size_t)row * DIM_E);
  int found_e = -1;
  float found_s = 0.f;
#pragma unroll
  for (int k = 0; k < 4; ++k) {
    const int p = lane + 64 * k;           // float4 position within row
    float4 v = rp[p];
    const int base = p * 4;
    if (v.x != 0.f) { found_e = base + 0; found_s = v.x; }
    if (v.y != 0.f) { found_e = base + 1; found_s = v.y; }
    if (v.z != 0.f) { found_e = base + 2; found_s = v.z; }
    if (v.w != 0.f) { found_e = base + 3; found_s = v.w; }
  }
  if (found_e >= 0) {
    const int slot = atomicAdd(&cursor[found_e], 1) + 1;  // cursor starts at -1
    if (slot < ELL_CAP) {
      const int entry = row | ((found_s < 0.f) ? 0x4000 : 0);
      // int4 group g = slot>>2 lives at ell4[g*1024 + e] (lane-consecutive e
      // -> coalesced int4 loads in the gather).
      ell[(slot >> 2) * (4 * DIM_E) + 4 * found_e + (slot & 3)] = entry;
    }
  }
}

// Decode one ELL entry against the LDS-staged x row.
//   q >= 0 : +-xs[j]  (sign from bit 14, applied via sign-bit XOR -- exact)
//   q == -1: +0.0f    (pad; address aliases to 16383 -> LDS broadcast)
__device__ __forceinline__ float ell_val(const float* xs, int q) {
  float v = xs[q & (DIM_D - 1)];
  int iv = __float_as_int(v);
  iv ^= (q & 0x4000) << 17;   // bit14 -> fp32 sign bit
  iv &= ~(q >> 31);           // pad -> 0.0f
  return __int_as_float(iv);
}

// K2: gather. One 1024-thread block per batch row. Stage the raw x row into
// LDS (pure copy, coalesced float4 -- sign now lives in the ELL entries).
// Thread e sums bucket e with a per-WAVE uniform trip count derived from
// cursor[] (wave-max ~26-28 slots vs global max ~40: ~30% fewer inner
// iterations, and no global atomicMax dependency).
__global__ __launch_bounds__(1024) void hash_gather(
    const float* __restrict__ x,
    const int* __restrict__ cursor,
    const int* __restrict__ ell,
    float* __restrict__ out) {
  __shared__ float xs[DIM_D];
  const int t = threadIdx.x;
  const int b = blockIdx.x;
  const float4* xp = (const float4*)(x + (size_t)b * DIM_D);
  float4* xs4 = (float4*)xs;
#pragma unroll
  for (int i = 0; i < DIM_D / 4 / 1024; ++i) {   // 4 float4s per thread
    const int p = t + i * 1024;
    xs4[p] = xp[p];
  }
  __syncthreads();

  // Per-wave uniform group count from the final bucket counts.
  int cnt = cursor[t] + 1;                       // cursor holds count-1
#pragma unroll
  for (int off = 32; off >= 1; off >>= 1)
    cnt = max(cnt, __shfl_xor(cnt, off));
  int G = (cnt + 3) >> 2;
  if (G > ELL_CAP / 4) G = ELL_CAP / 4;          // safety clamp

  const int4* ell4 = (const int4*)ell;
  float s0 = 0.f, s1 = 0.f, s2 = 0.f, s3 = 0.f;
  int4 q = ell4[t];                              // prefetch group 0
  for (int g = 1; g < G; ++g) {
    int4 qn = ell4[g * DIM_E + t];               // prefetch next group
    s0 += ell_val(xs, q.x);
    s1 += ell_val(xs, q.y);
    s2 += ell_val(xs, q.z);
    s3 += ell_val(xs, q.w);
    q = qn;
  }
  s0 += ell_val(xs, q.x);
  s1 += ell_val(xs, q.y);
  s2 += ell_val(xs, q.z);
  s3 += ell_val(xs, q.w);
  out[(size_t)b * DIM_E + t] = (s0 + s1) + (s2 + s3);
}

extern "C" void kernel_launch(void* const* d_in, const int* in_sizes, int n_in,
                              void* d_out, int out_size, void* d_ws, size_t ws_size,
                              hipStream_t stream) {
  const float* x = (const float*)d_in[0];
  const float* hashProj = (const float*)d_in[1];
  float* out = (float*)d_out;

  char* ws = (char*)d_ws;
  int* ell = (int*)ws;
  int* cursor = (int*)(ws + (size_t)ELL_CAP * DIM_E * sizeof(int));

  // Single prefill: ELL pads AND cursors both start at -1 (0xFF bytes).
  hipMemsetAsync(ws, 0xFF,
                 (size_t)ELL_CAP * DIM_E * sizeof(int) + DIM_E * sizeof(int),
                 stream);
  hash_extract_fill<<<DIM_D / 4, 256, 0, stream>>>(hashProj, cursor, ell);
  hash_gather<<<DIM_B, 1024, 0, stream>>>(x, cursor, ell, out);
}